// Round 2
// baseline (420.001 us; speedup 1.0000x reference)
//
#include <hip/hip_runtime.h>
#include <hip/hip_bf16.h>
#include <stdint.h>

#define NTOK 8192
#define DIM  1024
#define RD   128
#define NEXP 64
#define TOPK 8
#define MAXT 8192

// d_out element offsets (FLOAT32 elements — outputs concatenated f32)
#define W_OFF (NTOK * RD)            // 1048576
#define I_OFF (W_OFF + NTOK * TOPK)  // 1114112

// ws byte offsets
#define CNT_OFF  0
#define LIST_OFF 1024
#define WTS_OFF  (LIST_OFF + NEXP * MAXT * 4)              // 2098176
#define NT_OFF   (WTS_OFF + NTOK * TOPK * 4)               // 2360320
#define PW_OFF   (NT_OFF + (size_t)NEXP * RD * DIM * 2)    // 19137536
// total ws use = PW_OFF + NTOK*TOPK*RD*2 = 35,914,752 bytes

using bh8 = __attribute__((ext_vector_type(8))) short;
using fx4 = __attribute__((ext_vector_type(4))) float;

__device__ inline unsigned short f2bf(float f) {
    union { __hip_bfloat16 h; unsigned short u; } v;
    v.h = __float2bfloat16(f);
    return v.u;
}

// ---------------------------------------------------------------------------
// Kernel 0: neurons [e][d][r] f32  ->  nT [e][r][d] bf16  (B^T for MFMA)
// ---------------------------------------------------------------------------
__global__ __launch_bounds__(256) void nt_cast(const float* __restrict__ nr,
                                               __hip_bfloat16* __restrict__ nT) {
    int bx  = blockIdx.x;
    int e   = bx >> 5;            // 64 experts
    int sub = bx & 31;            // 16 d-tiles x 2 r-tiles
    int d0  = (sub >> 1) * 64;
    int r0  = (sub & 1) * 64;
    __shared__ float t[64][65];
    int tid = threadIdx.x;
    int dd  = tid >> 2;           // 0..63
    int rr4 = (tid & 3) * 16;     // 0,16,32,48
    const float* src = nr + ((size_t)e * DIM + d0 + dd) * RD + r0 + rr4;
    fx4 v[4];
    #pragma unroll
    for (int u = 0; u < 4; ++u) v[u] = ((const fx4*)src)[u];
    #pragma unroll
    for (int u = 0; u < 4; ++u)
        #pragma unroll
        for (int c = 0; c < 4; ++c) t[dd][rr4 + u * 4 + c] = v[u][c];
    __syncthreads();
    int rr  = tid >> 2;
    int dd4 = (tid & 3) * 16;
    union { unsigned short u[16]; uint4 q[2]; } o;
    #pragma unroll
    for (int i = 0; i < 16; ++i) o.u[i] = f2bf(t[dd4 + i][rr]);
    __hip_bfloat16* dst = nT + ((size_t)e * RD + r0 + rr) * DIM + d0 + dd4;
    ((uint4*)dst)[0] = o.q[0];
    ((uint4*)dst)[1] = o.q[1];
}

// ---------------------------------------------------------------------------
// Kernel 1: fp64 router scores + top-8 + softmax + dispatch lists
// block = 256 threads, 64 tokens
// ---------------------------------------------------------------------------
__global__ __launch_bounds__(256) void router_k(const float* __restrict__ x,
                                                const float* __restrict__ rw,
                                                int* __restrict__ cnt,
                                                int* __restrict__ lists,
                                                float* __restrict__ wts,
                                                float* __restrict__ out) {
    __shared__ __align__(16) char smem[2 * 64 * 68 * 4];
    float (*Xs)[68] = (float (*)[68])smem;
    float (*Ws)[68] = (float (*)[68])(smem + 64 * 68 * 4);
    double (*Ssc)[65] = (double (*)[65])smem;   // aliases Xs/Ws after compute

    int tid = threadIdx.x;
    int tb  = blockIdx.x * 64;
    int ni  = tid & 15;       // expert group base
    int ti  = tid >> 4;       // token group base (0..15)

    double acc[4][4];
    #pragma unroll
    for (int i = 0; i < 4; ++i)
        #pragma unroll
        for (int j = 0; j < 4; ++j) acc[i][j] = 0.0;

    int srow = tid >> 2;          // 0..63
    int scol = (tid & 3) * 16;    // 16 floats

    for (int c = 0; c < 16; ++c) {  // 16 chunks of 64 d
        const float* xs = x  + (size_t)(tb + srow) * DIM + c * 64 + scol;
        const float* ws = rw + (size_t)srow        * DIM + c * 64 + scol;
        fx4 xv[4], wv[4];
        #pragma unroll
        for (int u = 0; u < 4; ++u) { xv[u] = ((const fx4*)xs)[u]; wv[u] = ((const fx4*)ws)[u]; }
        __syncthreads();  // previous chunk's reads done
        #pragma unroll
        for (int u = 0; u < 4; ++u) {
            *(fx4*)&Xs[srow][scol + u * 4] = xv[u];
            *(fx4*)&Ws[srow][scol + u * 4] = wv[u];
        }
        __syncthreads();
        for (int dq = 0; dq < 64; dq += 4) {
            fx4 xa[4], wb[4];
            #pragma unroll
            for (int i = 0; i < 4; ++i) xa[i] = *(const fx4*)&Xs[ti + 16 * i][dq];
            #pragma unroll
            for (int j = 0; j < 4; ++j) wb[j] = *(const fx4*)&Ws[ni + 16 * j][dq];
            #pragma unroll
            for (int i = 0; i < 4; ++i)
                #pragma unroll
                for (int j = 0; j < 4; ++j)
                    acc[i][j] += (double)xa[i][0] * (double)wb[j][0]
                               + (double)xa[i][1] * (double)wb[j][1]
                               + (double)xa[i][2] * (double)wb[j][2]
                               + (double)xa[i][3] * (double)wb[j][3];
        }
    }
    __syncthreads();   // done reading Xs/Ws; safe to alias with Ssc
    #pragma unroll
    for (int i = 0; i < 4; ++i)
        #pragma unroll
        for (int j = 0; j < 4; ++j) Ssc[ti + 16 * i][ni + 16 * j] = acc[i][j];
    __syncthreads();

    if (tid < 64) {
        int t = tid, T = tb + tid;
        unsigned long long taken = 0;
        int idxs[TOPK];
        double svals[TOPK];
        #pragma unroll
        for (int p = 0; p < TOPK; ++p) {
            double best = -1e300; int bi = 0;
            for (int n = 0; n < NEXP; ++n) {
                if ((taken >> n) & 1ull) continue;
                double s = Ssc[t][n];
                if (s > best) { best = s; bi = n; }   // strict >: lowest index wins ties (lax.top_k)
            }
            taken |= 1ull << bi; idxs[p] = bi; svals[p] = best;
        }
        double m = svals[0], sum = 0.0, ex[TOPK];
        #pragma unroll
        for (int p = 0; p < TOPK; ++p) { ex[p] = exp(svals[p] - m); sum += ex[p]; }
        double inv = 1.0 / sum;
        #pragma unroll
        for (int p = 0; p < TOPK; ++p) {
            float w = (float)(ex[p] * inv);
            out[W_OFF + T * TOPK + p] = w;                 // weights, f32
            out[I_OFF + T * TOPK + p] = (float)idxs[p];    // indices as f32
            wts[T * TOPK + p] = w;
            int pos = atomicAdd(&cnt[idxs[p]], 1);
            lists[idxs[p] * MAXT + pos] = (T << 3) | p;
        }
    }
}

// ---------------------------------------------------------------------------
// Kernel 2: grouped gather-GEMM per expert. Tile 128 tok x 128 R, BK=64.
// A = gathered x rows (f32->bf16, XOR-swizzled LDS), B = nT via global_load_lds
// with pre-swizzled source. Epilogue applies softmax weight -> pw bf16.
// ---------------------------------------------------------------------------
__global__ __launch_bounds__(256) void gemm_k(const float* __restrict__ x,
                                              const __hip_bfloat16* __restrict__ nT,
                                              const int* __restrict__ cnt,
                                              const int* __restrict__ lists,
                                              const float* __restrict__ wts,
                                              __hip_bfloat16* __restrict__ pw) {
    int e = blockIdx.x >> 6;
    int j = blockIdx.x & 63;
    int ce = cnt[e];
    int base = j * 128;
    if (base >= ce) return;

    __shared__ __hip_bfloat16 As[128 * 64];   // 16 KB, swizzled
    __shared__ __hip_bfloat16 Bs[128 * 64];   // 16 KB, swizzled (rows = r, cols = d)
    __shared__ int   plist[128];
    __shared__ float wl[128];

    int tid = threadIdx.x;
    int wave = tid >> 6, lane = tid & 63;
    if (tid < 128) {
        int idx = base + tid;
        int p = (idx < ce) ? lists[e * MAXT + idx] : -1;
        plist[tid] = p;
        wl[tid] = (p >= 0) ? wts[p] : 0.0f;
    }
    __syncthreads();

    fx4 acc[4][4];
    #pragma unroll
    for (int a = 0; a < 4; ++a)
        #pragma unroll
        for (int b = 0; b < 4; ++b) acc[a][b] = (fx4){0.f, 0.f, 0.f, 0.f};

    const __hip_bfloat16* ntb = nT + (size_t)e * RD * DIM;
    int trow = tid >> 1;
    int seg  = tid & 1;
    int p_st = plist[trow];
    const float* xrow = (p_st >= 0) ? (x + (size_t)(p_st >> 3) * DIM + seg * 32) : nullptr;

    int wm = (wave >> 1) * 64, wn = (wave & 1) * 64;
    int lr = lane & 15, lk = (lane >> 4) * 8, lg = lane >> 4;

    for (int kt = 0; kt < 16; ++kt) {
        int d0 = kt * 64;
        // ---- stage A: 128 tok x 64 d, f32 -> bf16, swizzled ds_write
        {
            fx4 v[8];
            if (xrow) {
                const fx4* xs = (const fx4*)(xrow + d0);
                #pragma unroll
                for (int u = 0; u < 8; ++u) v[u] = xs[u];
            } else {
                #pragma unroll
                for (int u = 0; u < 8; ++u) v[u] = (fx4){0.f, 0.f, 0.f, 0.f};
            }
            #pragma unroll
            for (int q = 0; q < 4; ++q) {
                bh8 s;
                #pragma unroll
                for (int c = 0; c < 4; ++c) {
                    s[c]     = (short)f2bf(v[2 * q][c]);
                    s[4 + c] = (short)f2bf(v[2 * q + 1][c]);
                }
                unsigned bo = (unsigned)trow * 128 + (unsigned)(seg * 32 + q * 8) * 2;
                bo ^= (unsigned)(trow & 7) << 4;
                *(bh8*)((char*)As + bo) = s;
            }
        }
        // ---- stage B: 128 r x 64 d via global_load_lds (linear dest, pre-swizzled src)
        {
            #pragma unroll
            for (int c = 0; c < 4; ++c) {
                unsigned L = ((unsigned)(wave * 4 + c) * 64 + (unsigned)lane) * 16;
                unsigned row = L >> 7;            // 128 B per LDS row
                unsigned off = L & 127;
                unsigned soff = off ^ ((row & 7) << 4);
                const char* src = (const char*)ntb + ((size_t)row * DIM + d0) * 2 + soff;
                __builtin_amdgcn_global_load_lds(
                    (const __attribute__((address_space(1))) void*)src,
                    (__attribute__((address_space(3))) void*)((char*)Bs + (size_t)(wave * 4 + c) * 1024),
                    16, 0, 0);
            }
        }
        __syncthreads();
        // ---- MFMA: each wave 64 tok x 64 r
        #pragma unroll
        for (int kk = 0; kk < 2; ++kk) {
            int k0 = kk * 32;
            bh8 av[4], bv[4];
            #pragma unroll
            for (int mf = 0; mf < 4; ++mf) {
                unsigned row = (unsigned)(wm + mf * 16 + lr);
                unsigned bo = row * 128 + (unsigned)(k0 + lk) * 2;
                bo ^= (row & 7) << 4;
                av[mf] = *(const bh8*)((const char*)As + bo);
            }
            #pragma unroll
            for (int nf = 0; nf < 4; ++nf) {
                unsigned row = (unsigned)(wn + nf * 16 + lr);
                unsigned bo = row * 128 + (unsigned)(k0 + lk) * 2;
                bo ^= (row & 7) << 4;
                bv[nf] = *(const bh8*)((const char*)Bs + bo);
            }
            #pragma unroll
            for (int mf = 0; mf < 4; ++mf)
                #pragma unroll
                for (int nf = 0; nf < 4; ++nf)
                    acc[mf][nf] = __builtin_amdgcn_mfma_f32_16x16x32_bf16(av[mf], bv[nf], acc[mf][nf], 0, 0, 0);
        }
        __syncthreads();
    }
    // ---- epilogue: weight + store bf16 to pw[(t*8+k)*128 + r]
    #pragma unroll
    for (int mf = 0; mf < 4; ++mf) {
        #pragma unroll
        for (int rg = 0; rg < 4; ++rg) {
            int row = wm + mf * 16 + lg * 4 + rg;
            int p = plist[row];
            if (p < 0) continue;
            float wg = wl[row];
            #pragma unroll
            for (int nf = 0; nf < 4; ++nf) {
                int r = wn + nf * 16 + lr;
                pw[(size_t)p * RD + r] = __float2bfloat16(acc[mf][nf][rg] * wg);
            }
        }
    }
}

// ---------------------------------------------------------------------------
// Kernel 3: y[t][r] = sum_k pw[t][k][r]   (f32 output)
// ---------------------------------------------------------------------------
__global__ __launch_bounds__(256) void reduce_k(const __hip_bfloat16* __restrict__ pw,
                                                float* __restrict__ y) {
    int gid = blockIdx.x * 256 + threadIdx.x;  // 0..1048575
    int t = gid >> 7, r = gid & 127;
    float s = 0.f;
    #pragma unroll
    for (int k = 0; k < TOPK; ++k)
        s += __bfloat162float(pw[((size_t)t * TOPK + k) * RD + r]);
    y[gid] = s;
}

// ---------------------------------------------------------------------------
extern "C" void kernel_launch(void* const* d_in, const int* in_sizes, int n_in,
                              void* d_out, int out_size, void* d_ws, size_t ws_size,
                              hipStream_t stream) {
    const float* x  = (const float*)d_in[0];
    const float* rw = (const float*)d_in[1];
    const float* nr = (const float*)d_in[2];
    float* out = (float*)d_out;   // f32: output[1048576] | weights[65536] | idx[65536]
    char* ws = (char*)d_ws;
    int*   cnt   = (int*)(ws + CNT_OFF);
    int*   lists = (int*)(ws + LIST_OFF);
    float* wts   = (float*)(ws + WTS_OFF);
    __hip_bfloat16* nT = (__hip_bfloat16*)(ws + NT_OFF);
    __hip_bfloat16* pw = (__hip_bfloat16*)(ws + PW_OFF);

    hipMemsetAsync(cnt, 0, NEXP * sizeof(int), stream);
    nt_cast<<<2048, 256, 0, stream>>>(nr, nT);
    router_k<<<NTOK / 64, 256, 0, stream>>>(x, rw, cnt, lists, wts, out);
    gemm_k<<<NEXP * (MAXT / 128), 256, 0, stream>>>(x, nT, cnt, lists, wts, pw);
    reduce_k<<<(NTOK * RD) / 256, 256, 0, stream>>>(pw, out);
}

// Round 3
// 269.802 us; speedup vs baseline: 1.5567x; 1.5567x over previous
//
#include <hip/hip_runtime.h>
#include <hip/hip_bf16.h>
#include <stdint.h>

#define NTOK 8192
#define DIM  1024
#define RD   128
#define NEXP 64
#define TOPK 8
#define MAXT 8192

// d_out element offsets (f32 elements): output | weights | idx
#define W_OFF (NTOK * RD)            // 1048576
#define I_OFF (W_OFF + NTOK * TOPK)  // 1114112

// ws byte offsets (total 35,914,752 B — identical footprint to round 2)
#define CNT_OFF  0
#define LIST_OFF 1024
#define WTS_OFF  (LIST_OFF + NEXP * MAXT * 4)              // 2,098,176
#define NT_OFF   (WTS_OFF + NTOK * TOPK * 4)               // 2,360,320
#define XB_OFF   (NT_OFF + (size_t)NEXP * RD * DIM * 2)    // 19,137,536
// XB region (16 MB) is time-shared: Spart f64 [4][64][8192] during score/topk,
// then overwritten by xb bf16 [8192][1024] (x_cast runs AFTER topk_k).

using bh8 = __attribute__((ext_vector_type(8))) short;
using fx4 = __attribute__((ext_vector_type(4))) float;

__device__ inline unsigned short f2bf(float f) {
    union { __hip_bfloat16 h; unsigned short u; } v;
    v.h = __float2bfloat16(f);
    return v.u;
}

// ---------------------------------------------------------------------------
// Kernel 0: neurons [e][d][r] f32  ->  nT [e][r][d] bf16  (B^T for MFMA)
// ---------------------------------------------------------------------------
__global__ __launch_bounds__(256) void nt_cast(const float* __restrict__ nr,
                                               __hip_bfloat16* __restrict__ nT) {
    int bx  = blockIdx.x;
    int e   = bx >> 5;
    int sub = bx & 31;
    int d0  = (sub >> 1) * 64;
    int r0  = (sub & 1) * 64;
    __shared__ float t[64][65];
    int tid = threadIdx.x;
    int dd  = tid >> 2;
    int rr4 = (tid & 3) * 16;
    const float* src = nr + ((size_t)e * DIM + d0 + dd) * RD + r0 + rr4;
    fx4 v[4];
    #pragma unroll
    for (int u = 0; u < 4; ++u) v[u] = ((const fx4*)src)[u];
    #pragma unroll
    for (int u = 0; u < 4; ++u)
        #pragma unroll
        for (int c = 0; c < 4; ++c) t[dd][rr4 + u * 4 + c] = v[u][c];
    __syncthreads();
    int rr  = tid >> 2;
    int dd4 = (tid & 3) * 16;
    union { unsigned short u[16]; uint4 q[2]; } o;
    #pragma unroll
    for (int i = 0; i < 16; ++i) o.u[i] = f2bf(t[dd4 + i][rr]);
    __hip_bfloat16* dst = nT + ((size_t)e * RD + r0 + rr) * DIM + d0 + dd4;
    ((uint4*)dst)[0] = o.q[0];
    ((uint4*)dst)[1] = o.q[1];
}

// ---------------------------------------------------------------------------
// Kernel 1: x f32 -> xb bf16 (vectorized cast)
// ---------------------------------------------------------------------------
__global__ __launch_bounds__(256) void x_cast(const float* __restrict__ x,
                                              unsigned short* __restrict__ xb) {
    int gid = blockIdx.x * 256 + threadIdx.x;     // 1,048,576 threads, 8 f32 each
    const fx4* src = (const fx4*)(x + (size_t)gid * 8);
    fx4 a = src[0], b = src[1];
    bh8 o;
    #pragma unroll
    for (int c = 0; c < 4; ++c) { o[c] = (short)f2bf(a[c]); o[4 + c] = (short)f2bf(b[c]); }
    *(bh8*)(xb + (size_t)gid * 8) = o;
}

// ---------------------------------------------------------------------------
// Kernel 2: fp64 partial router scores, D-split x4.
// grid 512: ds = bid&3 (256-d slice), token tile = (bid>>2)*64.
// Writes Spart[ds][n][T] f64 (coalesced topk reads).
// ---------------------------------------------------------------------------
__global__ __launch_bounds__(256) void score_k(const float* __restrict__ x,
                                               const float* __restrict__ rw,
                                               double* __restrict__ sp) {
    __shared__ __align__(16) char smem[2 * 64 * 68 * 4];
    float (*Xs)[68] = (float (*)[68])smem;
    float (*Ws)[68] = (float (*)[68])(smem + 64 * 68 * 4);
    double (*Ssc)[65] = (double (*)[65])smem;   // 33,280 B, aliases after compute

    int tid = threadIdx.x;
    int ds  = blockIdx.x & 3;
    int tb  = (blockIdx.x >> 2) * 64;
    int ni  = tid & 15;
    int ti  = tid >> 4;

    double acc[4][4];
    #pragma unroll
    for (int i = 0; i < 4; ++i)
        #pragma unroll
        for (int j = 0; j < 4; ++j) acc[i][j] = 0.0;

    int srow = tid >> 2;
    int scol = (tid & 3) * 16;

    for (int c = 0; c < 4; ++c) {               // 4 chunks of 64 d (this block's 256-d slice)
        int d0 = (ds * 4 + c) * 64;
        const float* xs = x  + (size_t)(tb + srow) * DIM + d0 + scol;
        const float* ws = rw + (size_t)srow        * DIM + d0 + scol;
        fx4 xv[4], wv[4];
        #pragma unroll
        for (int u = 0; u < 4; ++u) { xv[u] = ((const fx4*)xs)[u]; wv[u] = ((const fx4*)ws)[u]; }
        __syncthreads();
        #pragma unroll
        for (int u = 0; u < 4; ++u) {
            *(fx4*)&Xs[srow][scol + u * 4] = xv[u];
            *(fx4*)&Ws[srow][scol + u * 4] = wv[u];
        }
        __syncthreads();
        for (int dq = 0; dq < 64; dq += 4) {
            fx4 xa[4], wb[4];
            #pragma unroll
            for (int i = 0; i < 4; ++i) xa[i] = *(const fx4*)&Xs[ti + 16 * i][dq];
            #pragma unroll
            for (int j = 0; j < 4; ++j) wb[j] = *(const fx4*)&Ws[ni + 16 * j][dq];
            #pragma unroll
            for (int i = 0; i < 4; ++i)
                #pragma unroll
                for (int j = 0; j < 4; ++j)
                    acc[i][j] += (double)xa[i][0] * (double)wb[j][0]
                               + (double)xa[i][1] * (double)wb[j][1]
                               + (double)xa[i][2] * (double)wb[j][2]
                               + (double)xa[i][3] * (double)wb[j][3];
        }
    }
    __syncthreads();
    #pragma unroll
    for (int i = 0; i < 4; ++i)
        #pragma unroll
        for (int j = 0; j < 4; ++j) Ssc[ti + 16 * i][ni + 16 * j] = acc[i][j];
    __syncthreads();

    // transposed writeout: Spart[ds][n][T], 128 B contiguous per thread
    int n  = tid >> 2;
    int t0 = (tid & 3) * 16;
    double* dst = sp + ((size_t)(ds * 64 + n) << 13) + tb + t0;
    #pragma unroll
    for (int k = 0; k < 16; ++k) dst[k] = Ssc[t0 + k][n];
}

// ---------------------------------------------------------------------------
// Kernel 3: per-token f64 top-8 (branchless sorted insert) + softmax + dispatch
// ---------------------------------------------------------------------------
__global__ __launch_bounds__(256) void topk_k(const double* __restrict__ sp,
                                              int* __restrict__ cnt,
                                              int* __restrict__ lists,
                                              float* __restrict__ wts,
                                              float* __restrict__ out) {
    int T = blockIdx.x * 256 + threadIdx.x;
    double vals[TOPK];
    int    idxs[TOPK];
    #pragma unroll
    for (int p = 0; p < TOPK; ++p) { vals[p] = -1e300; idxs[p] = 0; }

    for (int n = 0; n < NEXP; ++n) {
        // fixed-order partial sum: bit-exact, deterministic
        double s = sp[(size_t)n * NTOK + T]
                 + sp[(size_t)(64 + n) * NTOK + T]
                 + sp[(size_t)(128 + n) * NTOK + T]
                 + sp[(size_t)(192 + n) * NTOK + T];
        // branchless stable insert (strict >: lowest index wins ties, lax.top_k)
        #pragma unroll
        for (int jj = TOPK - 1; jj >= 1; --jj) {
            bool cj   = (s > vals[jj]);
            bool cjm1 = (s > vals[jj - 1]);
            vals[jj] = cj ? (cjm1 ? vals[jj - 1] : s) : vals[jj];
            idxs[jj] = cj ? (cjm1 ? idxs[jj - 1] : n) : idxs[jj];
        }
        if (s > vals[0]) { vals[0] = s; idxs[0] = n; }
    }

    double m = vals[0], sum = 0.0, ex[TOPK];
    #pragma unroll
    for (int p = 0; p < TOPK; ++p) { ex[p] = exp(vals[p] - m); sum += ex[p]; }
    double inv = 1.0 / sum;
    #pragma unroll
    for (int p = 0; p < TOPK; ++p) {
        float w = (float)(ex[p] * inv);
        out[W_OFF + T * TOPK + p] = w;
        out[I_OFF + T * TOPK + p] = (float)idxs[p];
        wts[T * TOPK + p] = w;
        int pos = atomicAdd(&cnt[idxs[p]], 1);
        lists[idxs[p] * MAXT + pos] = (T << 3) | p;
    }
}

// ---------------------------------------------------------------------------
// Kernel 4: grouped gather-GEMM. Tile 128 tok x 128 R, BK=64.
// BOTH A (gathered xb rows) and B (nT) staged via global_load_lds with
// pre-swizzled per-lane SOURCE + linear LDS dest (swizzle on read).
// Epilogue: f32 atomicAdd into zeroed out[] (replaces pw+reduce).
// Grid mapping e = bid&63 keeps an expert's blocks on one XCD (bid%8 = e%8).
// ---------------------------------------------------------------------------
__global__ __launch_bounds__(256) void gemm_k(const unsigned short* __restrict__ xb,
                                              const unsigned short* __restrict__ nTb,
                                              const int* __restrict__ cnt,
                                              const int* __restrict__ lists,
                                              const float* __restrict__ wts,
                                              float* __restrict__ outf) {
    int e = blockIdx.x & 63;
    int j = blockIdx.x >> 6;
    int ce = cnt[e];
    int base = j * 128;
    if (base >= ce) return;

    __shared__ unsigned short As[128 * 64];   // 16 KB, swizzled content, linear dest
    __shared__ unsigned short Bs[128 * 64];   // 16 KB
    __shared__ int   plist[128];
    __shared__ float wl[128];

    int tid = threadIdx.x;
    int wave = tid >> 6, lane = tid & 63;
    if (tid < 128) {
        int idx = base + tid;
        int p = (idx < ce) ? lists[e * MAXT + idx] : -1;
        plist[tid] = p;
        wl[tid] = (p >= 0) ? wts[p] : 0.0f;
    }
    __syncthreads();

    fx4 acc[4][4];
    #pragma unroll
    for (int a = 0; a < 4; ++a)
        #pragma unroll
        for (int b = 0; b < 4; ++b) acc[a][b] = (fx4){0.f, 0.f, 0.f, 0.f};

    // per-lane staging sources: lane covers 16 B at LDS row = (wave*4+c)*8 + (lane>>3),
    // within-row byte (lane&7)*16; inverse-swizzled source offset:
    unsigned soff = 16u * (unsigned)((lane & 7) ^ (lane >> 3));   // row&7 == lane>>3 here
    const char* asrc[4];
    const char* bsrc[4];
    const char* xbb = (const char*)xb;
    const char* ntb = (const char*)(nTb + (size_t)e * RD * DIM);
    #pragma unroll
    for (int c = 0; c < 4; ++c) {
        int row = (wave * 4 + c) * 8 + (lane >> 3);
        int p = plist[row];
        int tok = (p < 0) ? 0 : (p >> 3);
        asrc[c] = xbb + (size_t)tok * (DIM * 2) + soff;
        bsrc[c] = ntb + (size_t)row * (DIM * 2) + soff;
    }

    int wm = (wave >> 1) * 64, wn = (wave & 1) * 64;
    int lr = lane & 15, lk = (lane >> 4) * 8, lg = lane >> 4;

    for (int kt = 0; kt < 16; ++kt) {
        int db = kt * 128;   // d0 bytes (64 bf16)
        #pragma unroll
        for (int c = 0; c < 4; ++c) {
            __builtin_amdgcn_global_load_lds(
                (const __attribute__((address_space(1))) void*)(asrc[c] + db),
                (__attribute__((address_space(3))) void*)(As + (wave * 4 + c) * 512),
                16, 0, 0);
        }
        #pragma unroll
        for (int c = 0; c < 4; ++c) {
            __builtin_amdgcn_global_load_lds(
                (const __attribute__((address_space(1))) void*)(bsrc[c] + db),
                (__attribute__((address_space(3))) void*)(Bs + (wave * 4 + c) * 512),
                16, 0, 0);
        }
        __syncthreads();
        #pragma unroll
        for (int kk = 0; kk < 2; ++kk) {
            int k0 = kk * 32;
            bh8 av[4], bv[4];
            #pragma unroll
            for (int mf = 0; mf < 4; ++mf) {
                unsigned row = (unsigned)(wm + mf * 16 + lr);
                unsigned bo = row * 128 + (unsigned)(k0 + lk) * 2;
                bo ^= (row & 7) << 4;
                av[mf] = *(const bh8*)((const char*)As + bo);
            }
            #pragma unroll
            for (int nf = 0; nf < 4; ++nf) {
                unsigned row = (unsigned)(wn + nf * 16 + lr);
                unsigned bo = row * 128 + (unsigned)(k0 + lk) * 2;
                bo ^= (row & 7) << 4;
                bv[nf] = *(const bh8*)((const char*)Bs + bo);
            }
            #pragma unroll
            for (int mf = 0; mf < 4; ++mf)
                #pragma unroll
                for (int nf = 0; nf < 4; ++nf)
                    acc[mf][nf] = __builtin_amdgcn_mfma_f32_16x16x32_bf16(av[mf], bv[nf], acc[mf][nf], 0, 0, 0);
        }
        __syncthreads();
    }

    // epilogue: weighted f32 atomic accumulate into out[token][r]
    #pragma unroll
    for (int mf = 0; mf < 4; ++mf) {
        #pragma unroll
        for (int rg = 0; rg < 4; ++rg) {
            int row = wm + mf * 16 + lg * 4 + rg;
            int p = plist[row];
            if (p < 0) continue;
            float wg = wl[row];
            int t = p >> 3;
            #pragma unroll
            for (int nf = 0; nf < 4; ++nf) {
                int r = wn + nf * 16 + lr;
                atomicAdd(&outf[(size_t)t * RD + r], acc[mf][nf][rg] * wg);
            }
        }
    }
}

// ---------------------------------------------------------------------------
extern "C" void kernel_launch(void* const* d_in, const int* in_sizes, int n_in,
                              void* d_out, int out_size, void* d_ws, size_t ws_size,
                              hipStream_t stream) {
    const float* x  = (const float*)d_in[0];
    const float* rw = (const float*)d_in[1];
    const float* nr = (const float*)d_in[2];
    float* out = (float*)d_out;   // f32: output[1048576] | weights[65536] | idx[65536]
    char* ws = (char*)d_ws;
    int*    cnt   = (int*)(ws + CNT_OFF);
    int*    lists = (int*)(ws + LIST_OFF);
    float*  wts   = (float*)(ws + WTS_OFF);
    __hip_bfloat16* nT = (__hip_bfloat16*)(ws + NT_OFF);
    double* sp    = (double*)(ws + XB_OFF);          // Spart lives first...
    unsigned short* xbu = (unsigned short*)(ws + XB_OFF);  // ...then xb overwrites it

    hipMemsetAsync(cnt, 0, NEXP * sizeof(int), stream);
    hipMemsetAsync(out, 0, (size_t)NTOK * RD * sizeof(float), stream);
    nt_cast<<<2048, 256, 0, stream>>>(nr, nT);
    score_k<<<512, 256, 0, stream>>>(x, rw, sp);
    topk_k<<<NTOK / 256, 256, 0, stream>>>(sp, cnt, lists, wts, out);
    x_cast<<<4096, 256, 0, stream>>>(x, xbu);        // overwrites sp region (dead now)
    gemm_k<<<NEXP * 64, 256, 0, stream>>>(xbu, (const unsigned short*)nT, cnt, lists, wts, out);
}